// Round 9
// baseline (635.442 us; speedup 1.0000x reference)
//
#include <hip/hip_runtime.h>
#include <stdint.h>

#define B_ 512
#define D_ 512
#define C_ 100000
#define CK_ 300000
#define S_ 30.0f
#define COSM_ 0.8775825618903728f
#define SINM_ 0.4794255386042030f
#define TH_ (-0.8775825618903728f)
#define MM_ 0.2397127693021015f
#define EPS_ 1e-12f

#define BM 128
#define BN 96
#define BK 64
#define BUFU 6144    /* ushorts per B buffer: 12 frags x 512 */

typedef float f32x4 __attribute__((ext_vector_type(4)));
typedef short s16x8 __attribute__((ext_vector_type(8)));
typedef unsigned long long u64;
typedef unsigned int u32;

#define GLL16(g, l) __builtin_amdgcn_global_load_lds( \
    (const __attribute__((address_space(1))) void*)(g), \
    (__attribute__((address_space(3))) void*)(l), 16, 0, 0)

__device__ __forceinline__ unsigned short f2bf(float f){
  u32 u = __float_as_uint(f);
  u += 0x7FFFu + ((u >> 16) & 1u);
  return (unsigned short)(u >> 16);
}

// ---------------- normalize rows of [nrows, 512] fp32 -> unit bf16 ----------------
__global__ void k_norm(const float* __restrict__ src, unsigned short* __restrict__ dst){
  int row  = blockIdx.x * 4 + (threadIdx.x >> 6);
  int lane = threadIdx.x & 63;
  const float* r = src + (size_t)row * D_ + lane * 8;
  float4 v0 = *(const float4*)r;
  float4 v1 = *(const float4*)(r + 4);
  float s = v0.x*v0.x + v0.y*v0.y + v0.z*v0.z + v0.w*v0.w
          + v1.x*v1.x + v1.y*v1.y + v1.z*v1.z + v1.w*v1.w;
  #pragma unroll
  for (int off = 1; off < 64; off <<= 1) s += __shfl_xor(s, off);
  float inv = 1.f / fmaxf(sqrtf(s), EPS_);
  s16x8 h;
  h[0] = (short)f2bf(v0.x*inv); h[1] = (short)f2bf(v0.y*inv);
  h[2] = (short)f2bf(v0.z*inv); h[3] = (short)f2bf(v0.w*inv);
  h[4] = (short)f2bf(v1.x*inv); h[5] = (short)f2bf(v1.y*inv);
  h[6] = (short)f2bf(v1.z*inv); h[7] = (short)f2bf(v1.w*inv);
  *(s16x8*)(dst + (size_t)row * D_ + lane * 8) = h;
}

// ---------------- zero the per-row reduction buffers ----------------
__global__ void k_init(float* __restrict__ sumexp, u64* __restrict__ packed,
                       float* __restrict__ phi){
  int i = threadIdx.x;
  sumexp[i] = 0.f;
  packed[i] = 0ull;
  phi[i]    = 0.f;
}

// ======= PATH A GEMM: A from L2 (reg prefetch), B via gl_lds 3-buffer, 1 barrier/step =======
__global__ __launch_bounds__(256, 3) void k_gemm8(
    const unsigned short* __restrict__ xn, const unsigned short* __restrict__ wnb,
    const int* __restrict__ label,
    float* __restrict__ sumexp_g, u64* __restrict__ packed_g,
    float* __restrict__ phi_g)
{
  __shared__ unsigned short st[3*BUFU];   // 36864 B: B triple-buffer, frag-linear
  __shared__ int slab[BM];
  float* mx = (float*)st;                 // epilogue overlay [128][33]

  // bijective XCD-chunked mapping (12500 blocks = 8*1562 + 4)
  const int bid = blockIdx.x;
  const int xcd = bid & 7;
  const int i8  = bid >> 3;
  const int seq = (xcd < 4) ? (xcd*1563 + i8) : (6252 + (xcd-4)*1562 + i8);
  const int ct = seq >> 2;                 // column tile 0..3124
  const int rt = seq & 3;                  // row tile 0..3
  const int rowbase = rt * BM;
  const int lcbase  = ct * 32;

  const int tid  = threadIdx.x;
  const int lane = tid & 63;
  const int wid  = tid >> 6;
  const int wm   = wid >> 1, wn = wid & 1; // 2x2 wave grid, wave tile 64x48
  const int lc15 = lane & 15, lhi = lane >> 4;

  if (tid < BM) slab[tid] = label[rowbase + tid];

  // ---- A fragment sources (direct from L2-resident xn): row wm*64+m*16+lc15, k lhi*8
  const unsigned short* aptr[4];
  #pragma unroll
  for (int m = 0; m < 4; ++m)
    aptr[m] = xn + (size_t)(rowbase + wm*64 + m*16 + lc15) * D_ + lhi*8;

  // ---- B staging via gl_lds, frag-linear dest. pass p: frag f = 4p + wid, lane covers
  // row = class-permuted pos, k = ks*32 + (lane>>4)*8. dest = base + p*2048 + tid*8 (linear).
  const unsigned short* bsrc[3];
  #pragma unroll
  for (int p = 0; p < 3; ++p){
    int f    = 4*p + wid;                  // 0..11
    int wn_s = f / 6, rem = f - wn_s*6;
    int n_s  = rem >> 1, ks_s = rem & 1;
    int wrow = ct*BN + (wn_s*16 + lc15)*3 + n_s;   // subcenter n_s of class wn_s*16+lc15
    bsrc[p]  = wnb + (size_t)wrow * D_ + ks_s*32 + lhi*8;
  }

  // ---- B fragment read offsets: base + lane*16B (conflict-free linear)
  int boff[6];
  #pragma unroll
  for (int n = 0; n < 3; ++n)
    #pragma unroll
    for (int ks = 0; ks < 2; ++ks)
      boff[n*2+ks] = ((wn*3 + n)*2 + ks)*512 + lane*8;

  f32x4 acc[4][3] = {};
  s16x8 afA[8], afB[8];   // A frags, ping-pong: index q = ks*4 + m

  // ---- prologue: A(0) -> afA; B(0) -> buf0; B(1) -> buf1
  #pragma unroll
  for (int ks = 0; ks < 2; ++ks)
    #pragma unroll
    for (int m = 0; m < 4; ++m)
      afA[ks*4+m] = *(const s16x8*)(aptr[m] + ks*32);
  #pragma unroll
  for (int p = 0; p < 3; ++p) GLL16(bsrc[p], &st[p*2048 + tid*8]);
  #pragma unroll
  for (int p = 0; p < 3; ++p) GLL16(bsrc[p] + BK, &st[BUFU + p*2048 + tid*8]);
  asm volatile("s_waitcnt vmcnt(3)" ::: "memory");   // B(0) landed; B(1) in flight
  __builtin_amdgcn_s_barrier();

#define STEP(T, CUR, NXT) do{                                                   \
    if ((T) < 7){                                                               \
      const int ka = ((T)+1)*BK;                                                \
      _Pragma("unroll")                                                         \
      for (int ks = 0; ks < 2; ++ks)                                            \
        _Pragma("unroll")                                                       \
        for (int m = 0; m < 4; ++m)                                             \
          NXT[ks*4+m] = *(const s16x8*)(aptr[m] + ka + ks*32);                  \
    }                                                                           \
    if ((T) < 6){                                                               \
      const int kb = ((T)+2)*BK;                                                \
      unsigned short* db = &st[(((T)+2)%3)*BUFU];                               \
      _Pragma("unroll")                                                         \
      for (int p = 0; p < 3; ++p) GLL16(bsrc[p] + kb, db + p*2048 + tid*8);     \
    }                                                                           \
    {                                                                           \
      const unsigned short* cb = &st[((T)%3)*BUFU];                             \
      s16x8 bfr[6];                                                             \
      _Pragma("unroll")                                                         \
      for (int j = 0; j < 6; ++j) bfr[j] = *(const s16x8*)(cb + boff[j]);       \
      __builtin_amdgcn_s_setprio(1);                                            \
      _Pragma("unroll")                                                         \
      for (int ks = 0; ks < 2; ++ks)                                            \
        _Pragma("unroll")                                                       \
        for (int m = 0; m < 4; ++m)                                             \
          _Pragma("unroll")                                                     \
          for (int n = 0; n < 3; ++n)                                           \
            acc[m][n] = __builtin_amdgcn_mfma_f32_16x16x32_bf16(                \
                CUR[ks*4+m], bfr[n*2+ks], acc[m][n], 0, 0, 0);                  \
      __builtin_amdgcn_s_setprio(0);                                            \
    }                                                                           \
    if ((T) < 6)      asm volatile("s_waitcnt vmcnt(11)" ::: "memory");         \
    else if ((T)==6)  asm volatile("s_waitcnt vmcnt(8)"  ::: "memory");         \
    __builtin_amdgcn_s_barrier();                                               \
  }while(0)

  STEP(0, afA, afB);
  STEP(1, afB, afA);
  STEP(2, afA, afB);
  STEP(3, afB, afA);
  STEP(4, afA, afB);
  STEP(5, afB, afA);
  STEP(6, afA, afB);
  STEP(7, afB, afA);
#undef STEP

  // acc IS cosine (both operands unit bf16). Subcenter max in-register:
  // the 3 n-frags are the 3 subcenters of class (wn*16 + lc15).
  {
    int cls = wn*16 + lc15;
    #pragma unroll
    for (int m = 0; m < 4; ++m){
      #pragma unroll
      for (int r = 0; r < 4; ++r){
        int rl = wm*64 + m*16 + lhi*4 + r;
        float v = fmaxf(fmaxf(acc[m][0][r], acc[m][1][r]), acc[m][2][r]);
        if (slab[rl] - lcbase == cls){
          float cy = v;
          float s2 = fminf(fmaxf(1.f - cy*cy, 0.f), 1.f);
          float sy = sqrtf(s2);
          float ph = cy*COSM_ - sy*SINM_;
          if (!(cy - TH_ > 0.f)) ph = cy - MM_;
          phi_g[rowbase + rl] = ph;        // unique writer
          v = ph;
        }
        mx[rl*33 + cls] = v;               // overlay: safe, all LDS reads done
      }
    }
  }
  __syncthreads();

  // per-row LSE + argmax over this block's 32 classes: 2 threads per row
  {
    int row  = tid >> 1;
    int half = tid & 1;
    int grow = rowbase + row;
    float se = 0.f;
    u64 pk = 0ull;
    #pragma unroll
    for (int c = 0; c < 16; ++c){
      int lc = half*16 + c;
      float v = mx[row*33 + lc];
      se += __expf(S_*v - S_);
      u32 u = __float_as_uint(v);
      u = (v >= 0.f) ? (u | 0x80000000u) : ~u;            // sortable float
      u64 p = ((u64)u << 32) | (u32)~(u32)(lcbase + lc);  // ~idx: first-occurrence ties
      pk = (p > pk) ? p : pk;
    }
    se += __shfl_xor(se, 1);
    u32 lo = (u32)pk, hi2 = (u32)(pk >> 32);
    u32 plo = __shfl_xor(lo, 1), phi2 = __shfl_xor(hi2, 1);
    u64 po = ((u64)phi2 << 32) | plo;
    pk = (po > pk) ? po : pk;
    if (half == 0){
      atomicAdd(&sumexp_g[grow], se);
      atomicMax(&packed_g[grow], pk);
    }
  }
}

// ================= PATH B (fallback, ws too small): fused single-pass kernel =========
__global__ __launch_bounds__(256, 3) void k_gemm_fused(
    const unsigned short* __restrict__ xn, const float* __restrict__ w,
    const int* __restrict__ label,
    float* __restrict__ sumexp_g, u64* __restrict__ packed_g,
    float* __restrict__ phi_g)
{
  __shared__ union {
    struct { unsigned short a[BM*BK]; unsigned short b[BN*BK]; } st;
    float mx[BM*33];
  } sm;
  __shared__ float invs[BN];
  __shared__ int   slab[BM];

  const int bid = blockIdx.x;
  const int xcd = bid & 7;
  const int i8  = bid >> 3;
  const int seq = (xcd < 4) ? (xcd*1563 + i8) : (6252 + (xcd-4)*1562 + i8);
  const int ct = seq >> 2;
  const int rt = seq & 3;
  const int rowbase = rt * BM;
  const int colbase = ct * BN;

  const int tid  = threadIdx.x;
  const int lane = tid & 63;
  const int wid  = tid >> 6;
  const int wm   = wid >> 1, wn = wid & 1;
  const int lc15 = lane & 15, lhi = lane >> 4;

  if (tid < BM) slab[tid] = label[rowbase + tid];

  const int arow0 = tid >> 3, au = tid & 7;
  const unsigned short* asrc0 = xn + (size_t)(rowbase + arow0) * D_ + au * 8;
  const int adst0 = arow0 * BK + ((au * 8) ^ ((arow0 & 7) << 3));

  const int bc = tid >> 4, bu = tid & 15;
  const float* bsrc0 = w + (size_t)(colbase + bc * 3) * D_ + bu * 4;
  const int bdst0 = bc * BK + ((bu * 4) ^ ((bc & 7) << 3));

  const int swz = (lc15 & 7) << 3;
  int aoff[4][2], boff[3][2];
  #pragma unroll
  for (int m = 0; m < 4; ++m){
    int row = wm*64 + m*16 + lc15;
    #pragma unroll
    for (int ks = 0; ks < 2; ++ks) aoff[m][ks] = row * BK + ((ks*32 + lhi*8) ^ swz);
  }
  #pragma unroll
  for (int n = 0; n < 3; ++n){
    int row = wn*48 + n*16 + lc15;
    #pragma unroll
    for (int ks = 0; ks < 2; ++ks) boff[n][ks] = row * BK + ((ks*32 + lhi*8) ^ swz);
  }

  f32x4 acc[4][3] = {};
  float sq[6] = {0.f,0.f,0.f,0.f,0.f,0.f};

  for (int kt = 0; kt < D_/BK; ++kt){
    const int k0 = kt * BK;
    #pragma unroll
    for (int p = 0; p < 4; ++p){
      s16x8 v = *(const s16x8*)(asrc0 + (size_t)p*32*D_ + k0);
      *(s16x8*)(&sm.st.a[adst0 + p*32*BK]) = v;
    }
    #pragma unroll
    for (int p = 0; p < 6; ++p){
      float4 v = *(const float4*)(bsrc0 + (size_t)((p/3)*48 + (p%3)) * D_ + k0);
      sq[p] += v.x*v.x + v.y*v.y + v.z*v.z + v.w*v.w;
      ushort4 h;
      h.x = f2bf(v.x); h.y = f2bf(v.y); h.z = f2bf(v.z); h.w = f2bf(v.w);
      *(ushort4*)(&sm.st.b[bdst0 + p*16*BK]) = h;
    }
    __syncthreads();
    #pragma unroll
    for (int ks = 0; ks < 2; ++ks){
      s16x8 af[4], bfr[3];
      #pragma unroll
      for (int m = 0; m < 4; ++m) af[m]  = *(const s16x8*)(&sm.st.a[aoff[m][ks]]);
      #pragma unroll
      for (int n = 0; n < 3; ++n) bfr[n] = *(const s16x8*)(&sm.st.b[boff[n][ks]]);
      #pragma unroll
      for (int m = 0; m < 4; ++m)
        #pragma unroll
        for (int n = 0; n < 3; ++n)
          acc[m][n] = __builtin_amdgcn_mfma_f32_16x16x32_bf16(af[m], bfr[n], acc[m][n], 0, 0, 0);
    }
    __syncthreads();
  }

  #pragma unroll
  for (int p = 0; p < 6; ++p){
    float s = sq[p];
    s += __shfl_xor(s, 1); s += __shfl_xor(s, 2);
    s += __shfl_xor(s, 4); s += __shfl_xor(s, 8);
    if ((tid & 15) == 0) invs[p*16 + (tid >> 4)] = 1.f / fmaxf(sqrtf(s), EPS_);
  }
  __syncthreads();

  {
    float inv0 = invs[wn*48 +  0 + lc15];
    float inv1 = invs[wn*48 + 16 + lc15];
    float inv2 = invs[wn*48 + 32 + lc15];
    int cls    = wn*16 + lc15;
    int lcbase = ct * 32;
    #pragma unroll
    for (int m = 0; m < 4; ++m){
      #pragma unroll
      for (int r = 0; r < 4; ++r){
        int rl = wm*64 + m*16 + lhi*4 + r;
        float v = fmaxf(fmaxf(acc[m][0][r]*inv0, acc[m][1][r]*inv1), acc[m][2][r]*inv2);
        if (slab[rl] - lcbase == cls){
          float cy = v;
          float s2 = fminf(fmaxf(1.f - cy*cy, 0.f), 1.f);
          float sy = sqrtf(s2);
          float ph = cy*COSM_ - sy*SINM_;
          if (!(cy - TH_ > 0.f)) ph = cy - MM_;
          phi_g[rowbase + rl] = ph;
          v = ph;
        }
        sm.mx[rl*33 + cls] = v;
      }
    }
  }
  __syncthreads();

  {
    int row  = tid >> 1;
    int half = tid & 1;
    int grow = rowbase + row;
    float se = 0.f;
    u64 pk = 0ull;
    #pragma unroll
    for (int c = 0; c < 16; ++c){
      int lc = half*16 + c;
      float v = sm.mx[row*33 + lc];
      se += __expf(S_*v - S_);
      u32 u = __float_as_uint(v);
      u = (v >= 0.f) ? (u | 0x80000000u) : ~u;
      u64 p = ((u64)u << 32) | (u32)~(u32)(ct*32 + lc);
      pk = (p > pk) ? p : pk;
    }
    se += __shfl_xor(se, 1);
    u32 lo = (u32)pk, hi2 = (u32)(pk >> 32);
    u32 plo = __shfl_xor(lo, 1), phi2 = __shfl_xor(hi2, 1);
    u64 po = ((u64)phi2 << 32) | plo;
    pk = (po > pk) ? po : pk;
    if (half == 0){
      atomicAdd(&sumexp_g[grow], se);
      atomicMax(&packed_g[grow], pk);
    }
  }
}

// ---------------- finalize: loss + prec1 ----------------
__global__ void k_final(const float* __restrict__ sumexp, const u64* __restrict__ packed,
                        const float* __restrict__ phi, const int* __restrict__ label,
                        float* __restrict__ out){
  int i = threadIdx.x;
  float lse  = S_ + logf(sumexp[i]);
  float loss = lse - S_ * phi[i];
  u32 pred = ~(u32)(packed[i] & 0xFFFFFFFFull);
  float corr = (pred == (u32)label[i]) ? 1.f : 0.f;
  float a = loss, b = corr;
  #pragma unroll
  for (int off = 1; off < 64; off <<= 1){ a += __shfl_xor(a, off); b += __shfl_xor(b, off); }
  __shared__ float sa[8], sb[8];
  if ((i & 63) == 0){ sa[i >> 6] = a; sb[i >> 6] = b; }
  __syncthreads();
  if (i == 0){
    float ta = 0.f, tb = 0.f;
    #pragma unroll
    for (int j = 0; j < 8; ++j){ ta += sa[j]; tb += sb[j]; }
    out[0] = ta / 512.f;
    out[1] = tb * (100.f / 512.f);
  }
}

extern "C" void kernel_launch(void* const* d_in, const int* in_sizes, int n_in,
                              void* d_out, int out_size, void* d_ws, size_t ws_size,
                              hipStream_t stream){
  const float* x     = (const float*)d_in[0];
  const int*   label = (const int*)d_in[1];
  const float* w     = (const float*)d_in[2];
  float* out = (float*)d_out;
  char* ws = (char*)d_ws;

  unsigned short* xn = (unsigned short*)ws;            // 524288 B
  float* sumexp = (float*)(ws + 524288);               // 2048 B
  u64*   packed = (u64*)(ws + 524288 + 2048);          // 4096 B
  float* phi    = (float*)(ws + 524288 + 2048 + 4096); // 2048 B
  unsigned short* wnb = (unsigned short*)(ws + 532480);// 307,200,000 B (Path A)

  const size_t needA = 532480ull + (size_t)CK_ * D_ * 2ull;

  k_init <<<1,    512, 0, stream>>>(sumexp, packed, phi);
  k_norm <<<B_/4, 256, 0, stream>>>(x, xn);
  if (ws_size >= needA){
    k_norm <<<CK_/4, 256, 0, stream>>>(w, wnb);
    k_gemm8<<<(CK_/BN)*4, 256, 0, stream>>>(xn, wnb, label, sumexp, packed, phi);
  } else {
    k_gemm_fused<<<(CK_/BN)*4, 256, 0, stream>>>(xn, w, label, sumexp, packed, phi);
  }
  k_final<<<1,    512, 0, stream>>>(sumexp, packed, phi, label, out);
}

// Round 10
// 430.738 us; speedup vs baseline: 1.4752x; 1.4752x over previous
//
#include <hip/hip_runtime.h>
#include <stdint.h>

#define B_ 512
#define D_ 512
#define C_ 100000
#define CK_ 300000
#define S_ 30.0f
#define COSM_ 0.8775825618903728f
#define SINM_ 0.4794255386042030f
#define TH_ (-0.8775825618903728f)
#define MM_ 0.2397127693021015f
#define EPS_ 1e-12f

#define BM 512
#define BN 96
#define BK 32
#define BUFU 24576      /* ushorts per buffer: A 512x32 bf16 (16384) + B region 16KB (8192) */
#define NBLK 3125

typedef float f32x4 __attribute__((ext_vector_type(4)));
typedef short s16x8 __attribute__((ext_vector_type(8)));
typedef unsigned long long u64;
typedef unsigned int u32;

#define GLL16(g, l) __builtin_amdgcn_global_load_lds( \
    (const __attribute__((address_space(1))) void*)(g), \
    (__attribute__((address_space(3))) void*)(l), 16, 0, 0)

__device__ __forceinline__ unsigned short f2bf(float f){
  u32 u = __float_as_uint(f);
  u += 0x7FFFu + ((u >> 16) & 1u);
  return (unsigned short)(u >> 16);
}

// ---------------- normalize x rows -> unit bf16 ----------------
__global__ void k_normx(const float* __restrict__ x, unsigned short* __restrict__ xn){
  int row  = blockIdx.x * 4 + (threadIdx.x >> 6);
  int lane = threadIdx.x & 63;
  const float* xr = x + (size_t)row * D_ + lane * 8;
  float4 v0 = *(const float4*)xr;
  float4 v1 = *(const float4*)(xr + 4);
  float s = v0.x*v0.x + v0.y*v0.y + v0.z*v0.z + v0.w*v0.w
          + v1.x*v1.x + v1.y*v1.y + v1.z*v1.z + v1.w*v1.w;
  #pragma unroll
  for (int off = 1; off < 64; off <<= 1) s += __shfl_xor(s, off);
  float inv = 1.f / fmaxf(sqrtf(s), EPS_);
  s16x8 h;
  h[0] = (short)f2bf(v0.x*inv); h[1] = (short)f2bf(v0.y*inv);
  h[2] = (short)f2bf(v0.z*inv); h[3] = (short)f2bf(v0.w*inv);
  h[4] = (short)f2bf(v1.x*inv); h[5] = (short)f2bf(v1.y*inv);
  h[6] = (short)f2bf(v1.z*inv); h[7] = (short)f2bf(v1.w*inv);
  *(s16x8*)(xn + (size_t)row * D_ + lane * 8) = h;
}

// ---------------- zero the per-row reduction buffers ----------------
__global__ void k_init(float* __restrict__ sumexp, u64* __restrict__ packed,
                       float* __restrict__ phi){
  int i = threadIdx.x;
  sumexp[i] = 0.f;
  packed[i] = 0ull;
  phi[i]    = 0.f;
}

// ======= single-pass GEMM, BM=512: w fetched ONCE fp32; gl_lds; frag-linear; 3-buf =======
__global__ __launch_bounds__(512, 2) void k_gemm9(
    const unsigned short* __restrict__ xn, const float* __restrict__ w,
    const int* __restrict__ label,
    float* __restrict__ sumexp_g, u64* __restrict__ packed_g,
    float* __restrict__ phi_g)
{
  __shared__ unsigned short st[3*BUFU];   // 147456 B triple-buffered
  __shared__ int slab[BM];
  float* mx = (float*)st;                 // epilogue overlay [512][33] = 67584 B

  const int ct     = blockIdx.x;          // column tile: 32 classes (96 weight rows)
  const int lcbase = ct * 32;

  const int tid  = threadIdx.x;
  const int lane = tid & 63;
  const int wid  = tid >> 6;
  const int wm   = wid >> 1, wn = wid & 1;   // 4x2 wave grid, wave tile 128x48
  const int lc15 = lane & 15, lhi = lane >> 4;

  slab[tid] = label[tid];

  // ---- staging sources (kt-invariant); dest is ALWAYS bufbase + (p*512+tid)*16B.
  // A slots s=0..2047: frag fa=s>>6 (row fa*16+(s&15)), k-slice (s>>4)&3.
  const unsigned short* as4[4];
  #pragma unroll
  for (int p = 0; p < 4; ++p){
    int s   = p*512 + tid;
    int row = ((s >> 6) << 4) + (s & 15);
    as4[p]  = xn + (size_t)row * D_ + ((s >> 4) & 3) * 8;
  }
  // B slots sB=0..1023: frag fbp=sB>>7 (6,7 are L2-hit duplicates of 0,1 for pass
  // uniformity -> every thread issues exactly 6 gl_lds/step); hf=(sB>>6)&1.
  const float* bs2[2];
  #pragma unroll
  for (int p = 0; p < 2; ++p){
    int sB   = p*512 + tid;
    int fbp  = sB >> 7;
    int fbx  = fbp % 6;
    int hf   = (sB >> 6) & 1;
    int l    = sB & 63;
    int wn_s = fbx / 3, n_s = fbx % 3;
    int wrow = ct*BN + (wn_s*16 + (l & 15))*3 + n_s;   // subcenter n_s of class
    bs2[p]   = w + (size_t)wrow * D_ + ((l >> 4) & 3)*8 + hf*4;
  }

  // ---- fragment read offsets (conflict-free: base + lane*16B)
  int aoff[8];
  #pragma unroll
  for (int m = 0; m < 8; ++m) aoff[m] = (wm*8 + m)*512 + lane*8;     // ushort idx
  int boff[3];
  #pragma unroll
  for (int n = 0; n < 3; ++n) boff[n] = 16384/2*2/2 + 0;             // placeholder (computed below)
  #pragma unroll
  for (int n = 0; n < 3; ++n) boff[n] = 8192 + (wn*3 + n)*512 + lane*4;  // float idx in buffer

#define STAGE(BUFB, KT) do{                                                     \
    _Pragma("unroll")                                                           \
    for (int p = 0; p < 4; ++p)                                                 \
      GLL16(as4[p] + (KT)*32, &st[(BUFB) + (p*512 + tid)*8]);                   \
    _Pragma("unroll")                                                           \
    for (int p = 0; p < 2; ++p)                                                 \
      GLL16(bs2[p] + (KT)*32, &st[(BUFB) + ((p+4)*512 + tid)*8]);               \
  }while(0)

  f32x4 acc[8][3] = {};
  float sq[3] = {0.f, 0.f, 0.f};

  // ---- prologue: tiles 0,1 in flight
  STAGE(0, 0);
  STAGE(BUFU, 1);

  #pragma unroll
  for (int t = 0; t < 16; ++t){
    if (t < 14) STAGE(((t+2)%3)*BUFU, t+2);
    if (t < 14)       asm volatile("s_waitcnt vmcnt(12)" ::: "memory");  // tile t drained
    else if (t == 14) asm volatile("s_waitcnt vmcnt(6)"  ::: "memory");
    else              asm volatile("s_waitcnt vmcnt(0)"  ::: "memory");
    __builtin_amdgcn_s_barrier();
    asm volatile("" ::: "memory");
    {
      const unsigned short* ab = &st[(t%3)*BUFU];
      const float* bb = (const float*)ab;
      s16x8 af[8];
      #pragma unroll
      for (int m = 0; m < 8; ++m) af[m] = *(const s16x8*)(ab + aoff[m]);
      s16x8 bfr[3];
      #pragma unroll
      for (int n = 0; n < 3; ++n){
        f32x4 b0 = *(const f32x4*)(bb + boff[n]);
        f32x4 b1 = *(const f32x4*)(bb + boff[n] + 256);
        sq[n] += b0[0]*b0[0] + b0[1]*b0[1] + b0[2]*b0[2] + b0[3]*b0[3]
               + b1[0]*b1[0] + b1[1]*b1[1] + b1[2]*b1[2] + b1[3]*b1[3];
        union { s16x8 h; u32 u[4]; } pk;
        asm("v_cvt_pk_bf16_f32 %0, %1, %2" : "=v"(pk.u[0]) : "v"(b0[0]), "v"(b0[1]));
        asm("v_cvt_pk_bf16_f32 %0, %1, %2" : "=v"(pk.u[1]) : "v"(b0[2]), "v"(b0[3]));
        asm("v_cvt_pk_bf16_f32 %0, %1, %2" : "=v"(pk.u[2]) : "v"(b1[0]), "v"(b1[1]));
        asm("v_cvt_pk_bf16_f32 %0, %1, %2" : "=v"(pk.u[3]) : "v"(b1[2]), "v"(b1[3]));
        bfr[n] = pk.h;
      }
      #pragma unroll
      for (int m = 0; m < 8; ++m)
        #pragma unroll
        for (int n = 0; n < 3; ++n)
          acc[m][n] = __builtin_amdgcn_mfma_f32_16x16x32_bf16(af[m], bfr[n], acc[m][n], 0, 0, 0);
    }
    asm volatile("" ::: "memory");
    __builtin_amdgcn_s_barrier();
  }
#undef STAGE

  // ---- weight-row inverse norms: fold k-slices (each wave has its own exact copy)
  float inv[3];
  #pragma unroll
  for (int n = 0; n < 3; ++n){
    float s = sq[n];
    s += __shfl_xor(s, 16);
    s += __shfl_xor(s, 32);
    inv[n] = 1.f / fmaxf(sqrtf(s), EPS_);
  }

  // ---- subcenter max in-register; phi at label; write mx (overlay, post-barrier)
  {
    int cls = wn*16 + lc15;
    #pragma unroll
    for (int m = 0; m < 8; ++m){
      #pragma unroll
      for (int r = 0; r < 4; ++r){
        int rl = wm*128 + m*16 + lhi*4 + r;
        float v = fmaxf(fmaxf(acc[m][0][r]*inv[0], acc[m][1][r]*inv[1]), acc[m][2][r]*inv[2]);
        if (slab[rl] - lcbase == cls){
          float cy = v;
          float s2 = fminf(fmaxf(1.f - cy*cy, 0.f), 1.f);
          float sy = sqrtf(s2);
          float ph = cy*COSM_ - sy*SINM_;
          if (!(cy - TH_ > 0.f)) ph = cy - MM_;
          phi_g[rl] = ph;                  // unique writer (one ct owns each class)
          v = ph;
        }
        mx[rl*33 + cls] = v;
      }
    }
  }
  __syncthreads();

  // ---- per-row LSE + argmax over this block's 32 classes: 1 thread per row
  {
    float se = 0.f;
    u64 pk = 0ull;
    #pragma unroll 8
    for (int lc = 0; lc < 32; ++lc){
      float v = mx[tid*33 + lc];
      se += __expf(S_*v - S_);
      u32 u = __float_as_uint(v);
      u = (v >= 0.f) ? (u | 0x80000000u) : ~u;            // sortable float
      u64 p = ((u64)u << 32) | (u32)~(u32)(lcbase + lc);  // ~idx: first-occurrence ties
      pk = (p > pk) ? p : pk;
    }
    atomicAdd(&sumexp_g[tid], se);
    atomicMax(&packed_g[tid], pk);
  }
}

// ---------------- finalize: loss + prec1 ----------------
__global__ void k_final(const float* __restrict__ sumexp, const u64* __restrict__ packed,
                        const float* __restrict__ phi, const int* __restrict__ label,
                        float* __restrict__ out){
  int i = threadIdx.x;
  float lse  = S_ + logf(sumexp[i]);
  float loss = lse - S_ * phi[i];
  u32 pred = ~(u32)(packed[i] & 0xFFFFFFFFull);
  float corr = (pred == (u32)label[i]) ? 1.f : 0.f;
  float a = loss, b = corr;
  #pragma unroll
  for (int off = 1; off < 64; off <<= 1){ a += __shfl_xor(a, off); b += __shfl_xor(b, off); }
  __shared__ float sa[8], sb[8];
  if ((i & 63) == 0){ sa[i >> 6] = a; sb[i >> 6] = b; }
  __syncthreads();
  if (i == 0){
    float ta = 0.f, tb = 0.f;
    #pragma unroll
    for (int j = 0; j < 8; ++j){ ta += sa[j]; tb += sb[j]; }
    out[0] = ta / 512.f;
    out[1] = tb * (100.f / 512.f);
  }
}

extern "C" void kernel_launch(void* const* d_in, const int* in_sizes, int n_in,
                              void* d_out, int out_size, void* d_ws, size_t ws_size,
                              hipStream_t stream){
  const float* x     = (const float*)d_in[0];
  const int*   label = (const int*)d_in[1];
  const float* w     = (const float*)d_in[2];
  float* out = (float*)d_out;
  char* ws = (char*)d_ws;

  unsigned short* xn = (unsigned short*)ws;            // 524288 B
  float* sumexp = (float*)(ws + 524288);               // 2048 B
  u64*   packed = (u64*)(ws + 524288 + 2048);          // 4096 B
  float* phi    = (float*)(ws + 524288 + 2048 + 4096); // 2048 B

  k_init <<<1,    512, 0, stream>>>(sumexp, packed, phi);
  k_normx<<<B_/4, 256, 0, stream>>>(x, xn);
  k_gemm9<<<NBLK, 512, 0, stream>>>(xn, w, label, sumexp, packed, phi);
  k_final<<<1,    512, 0, stream>>>(sumexp, packed, phi, label, out);
}